// Round 2
// baseline (1630.975 us; speedup 1.0000x reference)
//
#include <hip/hip_runtime.h>
#include <hip/hip_bf16.h>
#include <hip/hip_fp16.h>

#define T_ 2048
#define B_ 64
#define NIN_ 128
#define H_ 256
#define NOUT_ 128
#define TB_ (T_*B_)

typedef _Float16 half2_t __attribute__((ext_vector_type(2)));

__device__ __forceinline__ half2_t mk2(_Float16 a, _Float16 b) { half2_t r; r.x = a; r.y = b; return r; }
__device__ __forceinline__ half2_t f2h2(float a, float b) { return mk2((_Float16)a, (_Float16)b); }
__device__ __forceinline__ half2_t h2cast(unsigned int u) { return __builtin_bit_cast(half2_t, u); }
__device__ __forceinline__ float fdot2(half2_t a, half2_t b, float c) {
    return __builtin_amdgcn_fdot2(a, b, c, false);
}

// ---------------------------------------------------------------------------
// K1: xp[TB][H] (f16) = x[TB][NIN](f32) @ w_ih^T + (b_ih + b_hh)
// block tile: 128 rows x 256 cols; thread: rows [rh*64,+64), cols {c, c+128}
// ---------------------------------------------------------------------------
__global__ __launch_bounds__(256, 2) void k1_xproj(
    const float* __restrict__ x,
    const float* __restrict__ w_ih,
    const float* __restrict__ b_ih,
    const float* __restrict__ b_hh,
    _Float16* __restrict__ xp)
{
    __shared__ __align__(16) _Float16 xs[128 * 128];   // 32 KB
    const int tid = threadIdx.x;
    const long row0 = (long)blockIdx.x * 128;

    const float4* xg = (const float4*)(x + row0 * NIN_);
    #pragma unroll
    for (int it = 0; it < 16; ++it) {
        int idx = tid + it * 256;
        float4 d = xg[idx];
        half2_t* dst = (half2_t*)&xs[idx * 4];
        dst[0] = f2h2(d.x, d.y);
        dst[1] = f2h2(d.z, d.w);
    }

    const int c = tid & 127;
    const int rh = tid >> 7;
    half2_t w0[64], w1[64];
    const float4* wg0 = (const float4*)(w_ih + (long)c * NIN_);
    const float4* wg1 = (const float4*)(w_ih + (long)(c + 128) * NIN_);
    #pragma unroll
    for (int it = 0; it < 32; ++it) {
        float4 d0 = wg0[it];
        w0[2*it]   = f2h2(d0.x, d0.y);
        w0[2*it+1] = f2h2(d0.z, d0.w);
        float4 d1 = wg1[it];
        w1[2*it]   = f2h2(d1.x, d1.y);
        w1[2*it+1] = f2h2(d1.z, d1.w);
    }
    const float bias0 = b_ih[c] + b_hh[c];
    const float bias1 = b_ih[c + 128] + b_hh[c + 128];
    __syncthreads();

    for (int r = rh * 64; r < rh * 64 + 64; ++r) {
        const uint4* xr = (const uint4*)&xs[r * 128];
        float a0=0,a1=0,a2=0,a3=0, c0=0,c1=0,c2=0,c3=0;
        #pragma unroll
        for (int k0 = 0; k0 < 16; ++k0) {
            uint4 hv = xr[k0];
            half2_t x0=h2cast(hv.x), x1=h2cast(hv.y), x2=h2cast(hv.z), x3=h2cast(hv.w);
            a0 = fdot2(x0, w0[4*k0+0], a0);
            a1 = fdot2(x1, w0[4*k0+1], a1);
            a2 = fdot2(x2, w0[4*k0+2], a2);
            a3 = fdot2(x3, w0[4*k0+3], a3);
            c0 = fdot2(x0, w1[4*k0+0], c0);
            c1 = fdot2(x1, w1[4*k0+1], c1);
            c2 = fdot2(x2, w1[4*k0+2], c2);
            c3 = fdot2(x3, w1[4*k0+3], c3);
        }
        float s0 = ((a0+a1)+(a2+a3)) + bias0;
        float s1 = ((c0+c1)+(c2+c3)) + bias1;
        _Float16* dst = xp + (row0 + r) * H_;
        dst[c]       = (_Float16)s0;
        dst[c + 128] = (_Float16)s1;
    }
}

// ---------------------------------------------------------------------------
// K2: sequential scan. 64 WGs (one per batch element), 256 threads.
// Thread j owns output h[j]; W_hh row j lives in 128 half2 VGPRs.
// h double-buffered in LDS (broadcast reads), 1 barrier/step.
// ---------------------------------------------------------------------------
__global__ __launch_bounds__(256, 1) void k2_scan(
    const _Float16* __restrict__ xp,       // [T][B][H] f16
    const float* __restrict__ w_hh,        // [H][H] f32
    _Float16* __restrict__ hs)             // [T][B][H] f16
{
    const int b = blockIdx.x;
    const int j = threadIdx.x;

    half2_t w[128];
    const float4* wg = (const float4*)(w_hh + (long)j * H_);
    #pragma unroll
    for (int it = 0; it < 64; ++it) {
        float4 d = wg[it];
        w[2*it]   = f2h2(d.x, d.y);
        w[2*it+1] = f2h2(d.z, d.w);
    }

    __shared__ __align__(16) _Float16 hbuf[2][256];
    hbuf[0][j] = (_Float16)0.0f;
    __syncthreads();

    const _Float16* xpb = xp + (long)b * H_ + j;
    float xbuf[4];
    #pragma unroll
    for (int i = 0; i < 4; ++i) xbuf[i] = (float)xpb[(long)i * (B_ * H_)];

    _Float16* hsout = hs + (long)b * H_ + j;

    for (int t = 0; t < T_; t += 4) {
        #pragma unroll
        for (int u = 0; u < 4; ++u) {
            const int tt = t + u;
            const float xv = xbuf[u];
            const int tpf = (tt + 4 < T_) ? (tt + 4) : (T_ - 1);
            xbuf[u] = (float)xpb[(long)tpf * (B_ * H_)];   // prefetch 4 steps ahead

            const uint4* hv4 = (const uint4*)&hbuf[tt & 1][0];
            float a[8] = {0,0,0,0,0,0,0,0};
            #pragma unroll
            for (int k0 = 0; k0 < 32; ++k0) {
                uint4 hv = hv4[k0];
                a[(4*k0+0)&7] = fdot2(h2cast(hv.x), w[4*k0+0], a[(4*k0+0)&7]);
                a[(4*k0+1)&7] = fdot2(h2cast(hv.y), w[4*k0+1], a[(4*k0+1)&7]);
                a[(4*k0+2)&7] = fdot2(h2cast(hv.z), w[4*k0+2], a[(4*k0+2)&7]);
                a[(4*k0+3)&7] = fdot2(h2cast(hv.w), w[4*k0+3], a[(4*k0+3)&7]);
            }
            float s = (((a[0]+a[1])+(a[2]+a[3])) + ((a[4]+a[5])+(a[6]+a[7]))) + xv;
            // tanh(s) = 1 - 2/(e^{2s}+1); saturates correctly at +-inf
            float e  = __expf(2.0f * s);
            float hn = 1.0f - 2.0f * __builtin_amdgcn_rcpf(e + 1.0f);
            _Float16 hh = (_Float16)hn;
            hbuf[(tt + 1) & 1][j] = hh;
            hsout[(long)tt * (B_ * H_)] = hh;
            __syncthreads();   // writes of step tt visible before reads of tt+1
        }
    }
}

// ---------------------------------------------------------------------------
// K3: out[TB][NOUT] (f32) = hs[TB][H](f16) @ w_out^T + b_out
// block tile: 128 rows x 128 cols; thread: rows [rh*64,+64), col c
// ---------------------------------------------------------------------------
__global__ __launch_bounds__(256, 2) void k3_out(
    const _Float16* __restrict__ hs,
    const float* __restrict__ w_out,
    const float* __restrict__ b_out,
    float* __restrict__ out)
{
    __shared__ __align__(16) _Float16 hl[128 * 256];   // 64 KB
    const int tid = threadIdx.x;
    const long row0 = (long)blockIdx.x * 128;

    const uint4* hg = (const uint4*)(hs + row0 * H_);
    uint4* hld = (uint4*)hl;
    #pragma unroll
    for (int it = 0; it < 16; ++it) {
        int idx = tid + it * 256;
        hld[idx] = hg[idx];
    }

    const int c = tid & 127;
    const int rh = tid >> 7;
    half2_t w[128];
    const float4* wg = (const float4*)(w_out + (long)c * H_);
    #pragma unroll
    for (int it = 0; it < 64; ++it) {
        float4 d = wg[it];
        w[2*it]   = f2h2(d.x, d.y);
        w[2*it+1] = f2h2(d.z, d.w);
    }
    const float bias = b_out[c];
    __syncthreads();

    for (int r = rh * 64; r < rh * 64 + 64; ++r) {
        const uint4* hr = (const uint4*)&hl[r * 256];
        float a[8] = {0,0,0,0,0,0,0,0};
        #pragma unroll
        for (int k0 = 0; k0 < 32; ++k0) {
            uint4 hv = hr[k0];
            a[(4*k0+0)&7] = fdot2(h2cast(hv.x), w[4*k0+0], a[(4*k0+0)&7]);
            a[(4*k0+1)&7] = fdot2(h2cast(hv.y), w[4*k0+1], a[(4*k0+1)&7]);
            a[(4*k0+2)&7] = fdot2(h2cast(hv.z), w[4*k0+2], a[(4*k0+2)&7]);
            a[(4*k0+3)&7] = fdot2(h2cast(hv.w), w[4*k0+3], a[(4*k0+3)&7]);
        }
        float s = (((a[0]+a[1])+(a[2]+a[3])) + ((a[4]+a[5])+(a[6]+a[7]))) + bias;
        out[(row0 + r) * NOUT_ + c] = s;
    }
}

extern "C" void kernel_launch(void* const* d_in, const int* in_sizes, int n_in,
                              void* d_out, int out_size, void* d_ws, size_t ws_size,
                              hipStream_t stream) {
    const float* x     = (const float*)d_in[0];
    const float* w_ih  = (const float*)d_in[1];
    const float* w_hh  = (const float*)d_in[2];
    const float* b_ih  = (const float*)d_in[3];
    const float* b_hh  = (const float*)d_in[4];
    const float* w_out = (const float*)d_in[5];
    const float* b_out = (const float*)d_in[6];

    _Float16* xp    = (_Float16*)d_ws;                 // 67.1 MB
    _Float16* hsbuf = xp + (size_t)TB_ * H_;           // 67.1 MB

    k1_xproj<<<TB_ / 128, 256, 0, stream>>>(x, w_ih, b_ih, b_hh, xp);
    k2_scan <<<B_,        256, 0, stream>>>(xp, w_hh, hsbuf);
    k3_out  <<<TB_ / 128, 256, 0, stream>>>(hsbuf, w_out, b_out, (float*)d_out);
}